// Round 5
// baseline (40.616 us; speedup 1.0000x reference)
//
#include <hip/hip_runtime.h>
#include <cfloat>

// Problem dims (fixed by reference)
#define BB   256   // batch
#define DIM  512
#define NN   196
#define BT   4     // b-tile in prep kernels
#define IT   32    // i-tile in prep kernels

// ---------------------------------------------------------------------------
// Kernel 0: transpose W_concat into WCt[k][i] = (W_concat[i][k], W_concat[DIM+i][k])
// grid (8,8) x 256 threads, 64x64 tiles via LDS.
// ---------------------------------------------------------------------------
__global__ __launch_bounds__(256) void transpose_kernel(
    const float* __restrict__ Wc,    // (2*DIM, DIM)
    float2* __restrict__ WCt)        // (DIM, DIM) of (c1,c2)
{
    __shared__ float2 T[64][65];
    const int tid = threadIdx.x;
    const int i0 = blockIdx.x * 64, k0 = blockIdx.y * 64;
    const int r  = tid >> 2;          // 0..63 i-row
    const int cb = (tid & 3) * 16;    // k base (16 floats per thread)
    #pragma unroll
    for (int j = 0; j < 16; j += 4) {
        const float4 a = *(const float4*)&Wc[(size_t)(i0 + r) * DIM + k0 + cb + j];
        const float4 b = *(const float4*)&Wc[(size_t)(DIM + i0 + r) * DIM + k0 + cb + j];
        T[cb + j + 0][r] = make_float2(a.x, b.x);
        T[cb + j + 1][r] = make_float2(a.y, b.y);
        T[cb + j + 2][r] = make_float2(a.z, b.z);
        T[cb + j + 3][r] = make_float2(a.w, b.w);
    }
    __syncthreads();
    const int ii = tid & 63;
    const int kq = tid >> 6;          // 0..3
    #pragma unroll
    for (int kk = 0; kk < 16; ++kk) {
        const int k = kq * 16 + kk;
        WCt[(size_t)(k0 + k) * DIM + i0 + ii] = T[k][ii];
    }
}

// ---------------------------------------------------------------------------
// Kernel 1 (fast path): prep — w[b,i] = (mem[b,i]+b_mem[i])*v1[b,i] + v2[b,i]
// Barrier-free main loop: per k-step 2 coalesced global loads (W_mem, WCt,
// both L2-hot) + 2 LDS broadcasts (MU) + 12 FMA. Thread (kg=tid>>5, il):
// contiguous 64-k slice, one i, 4 b. grid (64,16), 4 blocks/CU.
// ---------------------------------------------------------------------------
__global__ __launch_bounds__(256, 4) void prep_fast(
    const float* __restrict__ memory,    // (2,BB,DIM)
    const float* __restrict__ control,   // (2,BB,DIM)
    const float* __restrict__ W_mem,     // (DIM,DIM) [d][i]
    const float* __restrict__ b_mem,     // (DIM)
    const float2* __restrict__ WCt,      // (DIM,DIM) of (c1,c2), [k][i]
    const float* __restrict__ W_attn,    // (DIM,1)
    float* __restrict__ w_out)           // (BB, DIM)
{
    __shared__ float4 MU[DIM * 2];   // 16 KB: [k*2+0]=(m0,u0,m1,u1) [k*2+1]=(m2,u2,m3,u3)
    __shared__ float  P[3072];       // 12 KB epilogue partials

    const int tid = threadIdx.x;
    const int il  = tid & 31;        // i within tile
    const int kg  = tid >> 5;        // 0..7 k-group (64-k contiguous slice)
    const int b0  = blockIdx.x * BT;
    const int i0  = blockIdx.y * IT;

    const float* mem_in = memory  + (size_t)BB * DIM;  // memory[-1]
    const float* ctl_in = control + (size_t)BB * DIM;  // control[-1]

    // ---- stage MU once: 1024 float4 by 256 threads, coalesced over k ----
    #pragma unroll
    for (int p = 0; p < 4; ++p) {
        const int idx  = p * 256 + tid;       // 0..1023
        const int pair = idx >> 9;            // 0..1
        const int k    = idx & 511;
        const int bb   = b0 + pair * 2;
        const float wa = W_attn[k];
        MU[k * 2 + pair] = make_float4(
            mem_in[(size_t)bb       * DIM + k],
            ctl_in[(size_t)bb       * DIM + k] * wa,
            mem_in[(size_t)(bb + 1) * DIM + k],
            ctl_in[(size_t)(bb + 1) * DIM + k] * wa);
    }
    __syncthreads();

    float am0 = 0.f, am1 = 0.f, am2 = 0.f, am3 = 0.f;
    float a10 = 0.f, a11 = 0.f, a12 = 0.f, a13 = 0.f;
    float a20 = 0.f, a21 = 0.f, a22 = 0.f, a23 = 0.f;

    const float*  wmp = &W_mem[(size_t)(kg * 64) * DIM + i0 + il];
    const float2* wcp = &WCt [(size_t)(kg * 64) * DIM + i0 + il];
    const float4* mup = &MU[(kg * 64) * 2];

    #pragma unroll 8
    for (int kk = 0; kk < 64; ++kk) {
        const float  wm   = wmp[(size_t)kk * DIM];   // 2x128B/wave, L2-hot
        const float2 c    = wcp[(size_t)kk * DIM];   // 2x256B/wave, L2-hot
        const float4 mu01 = mup[kk * 2 + 0];         // LDS broadcast
        const float4 mu23 = mup[kk * 2 + 1];
        am0 = fmaf(mu01.x, wm,  am0);
        a10 = fmaf(mu01.y, c.x, a10);
        a20 = fmaf(mu01.y, c.y, a20);
        am1 = fmaf(mu01.z, wm,  am1);
        a11 = fmaf(mu01.w, c.x, a11);
        a21 = fmaf(mu01.w, c.y, a21);
        am2 = fmaf(mu23.x, wm,  am2);
        a12 = fmaf(mu23.y, c.x, a12);
        a22 = fmaf(mu23.y, c.y, a22);
        am3 = fmaf(mu23.z, wm,  am3);
        a13 = fmaf(mu23.w, c.x, a13);
        a23 = fmaf(mu23.w, c.y, a23);
    }

    // ---- combine 8 k-group partials in LDS ----
    __syncthreads();
    {
        const int base = kg * 4;
        P[((base + 0) * 3 + 0) * 32 + il] = am0;
        P[((base + 0) * 3 + 1) * 32 + il] = a10;
        P[((base + 0) * 3 + 2) * 32 + il] = a20;
        P[((base + 1) * 3 + 0) * 32 + il] = am1;
        P[((base + 1) * 3 + 1) * 32 + il] = a11;
        P[((base + 1) * 3 + 2) * 32 + il] = a21;
        P[((base + 2) * 3 + 0) * 32 + il] = am2;
        P[((base + 2) * 3 + 1) * 32 + il] = a12;
        P[((base + 2) * 3 + 2) * 32 + il] = a22;
        P[((base + 3) * 3 + 0) * 32 + il] = am3;
        P[((base + 3) * 3 + 1) * 32 + il] = a13;
        P[((base + 3) * 3 + 2) * 32 + il] = a23;
    }
    __syncthreads();
    if (tid < 128) {
        const int b = tid >> 5, ii = tid & 31;
        float sm = 0.f, s1 = 0.f, s2 = 0.f;
        #pragma unroll
        for (int t = 0; t < 8; ++t) {
            sm += P[((t * 4 + b) * 3 + 0) * 32 + ii];
            s1 += P[((t * 4 + b) * 3 + 1) * 32 + ii];
            s2 += P[((t * 4 + b) * 3 + 2) * 32 + ii];
        }
        w_out[(size_t)(b0 + b) * DIM + i0 + ii] = (sm + b_mem[i0 + ii]) * s1 + s2;
    }
}

// ---------------------------------------------------------------------------
// Kernel 1 (fallback, r4-proven): used only if ws_size is too small for WCt.
// ---------------------------------------------------------------------------
__global__ __launch_bounds__(256, 4) void prep_kernel(
    const float* __restrict__ memory, const float* __restrict__ control,
    const float* __restrict__ W_mem, const float* __restrict__ b_mem,
    const float* __restrict__ W_concat, const float* __restrict__ W_attn,
    float* __restrict__ w_out)
{
    __shared__ float4 MU[DIM * 2];
    __shared__ float  WTb[4224];

    const int tid = threadIdx.x;
    const int il  = tid & 31;
    const int kg  = tid >> 5;
    const int b0  = blockIdx.x * BT;
    const int i0  = blockIdx.y * IT;

    const float* mem_in = memory  + (size_t)BB * DIM;
    const float* ctl_in = control + (size_t)BB * DIM;

    #pragma unroll
    for (int p = 0; p < 4; ++p) {
        const int idx  = p * 256 + tid;
        const int pair = idx >> 9;
        const int k    = idx & 511;
        const int bb   = b0 + pair * 2;
        const float wa = W_attn[k];
        MU[k * 2 + pair] = make_float4(
            mem_in[(size_t)bb       * DIM + k],
            ctl_in[(size_t)bb       * DIM + k] * wa,
            mem_in[(size_t)(bb + 1) * DIM + k],
            ctl_in[(size_t)(bb + 1) * DIM + k] * wa);
    }

    float am0 = 0.f, am1 = 0.f, am2 = 0.f, am3 = 0.f;
    float a10 = 0.f, a11 = 0.f, a12 = 0.f, a13 = 0.f;
    float a20 = 0.f, a21 = 0.f, a22 = 0.f, a23 = 0.f;

    float2* WT = (float2*)WTb;
    const int sr = tid >> 3;
    const int sc = tid & 7;

    for (int kt = 0; kt < DIM; kt += 64) {
        __syncthreads();
        {
            const float* w1p = &W_concat[(size_t)(i0 + sr) * DIM + kt + sc * 8];
            const float* w2p = w1p + (size_t)DIM * DIM;
            const float4 q1a = *(const float4*)w1p;
            const float4 q1b = *(const float4*)(w1p + 4);
            const float4 q2a = *(const float4*)w2p;
            const float4 q2b = *(const float4*)(w2p + 4);
            const int kb = sc * 8;
            WT[(kb + 0) * 33 + sr] = make_float2(q1a.x, q2a.x);
            WT[(kb + 1) * 33 + sr] = make_float2(q1a.y, q2a.y);
            WT[(kb + 2) * 33 + sr] = make_float2(q1a.z, q2a.z);
            WT[(kb + 3) * 33 + sr] = make_float2(q1a.w, q2a.w);
            WT[(kb + 4) * 33 + sr] = make_float2(q1b.x, q2b.x);
            WT[(kb + 5) * 33 + sr] = make_float2(q1b.y, q2b.y);
            WT[(kb + 6) * 33 + sr] = make_float2(q1b.z, q2b.z);
            WT[(kb + 7) * 33 + sr] = make_float2(q1b.w, q2b.w);
        }
        __syncthreads();
        #pragma unroll
        for (int kk = 0; kk < 8; ++kk) {
            const int kl = kg * 8 + kk;
            const int k  = kt + kl;
            const float  wm   = W_mem[(size_t)k * DIM + i0 + il];
            const float2 c    = WT[kl * 33 + il];
            const float4 mu01 = MU[k * 2 + 0];
            const float4 mu23 = MU[k * 2 + 1];
            am0 = fmaf(mu01.x, wm,  am0);
            a10 = fmaf(mu01.y, c.x, a10);
            a20 = fmaf(mu01.y, c.y, a20);
            am1 = fmaf(mu01.z, wm,  am1);
            a11 = fmaf(mu01.w, c.x, a11);
            a21 = fmaf(mu01.w, c.y, a21);
            am2 = fmaf(mu23.x, wm,  am2);
            a12 = fmaf(mu23.y, c.x, a12);
            a22 = fmaf(mu23.y, c.y, a22);
            am3 = fmaf(mu23.z, wm,  am3);
            a13 = fmaf(mu23.w, c.x, a13);
            a23 = fmaf(mu23.w, c.y, a23);
        }
    }

    __syncthreads();
    {
        float* Pp = WTb;
        const int base = kg * 4;
        Pp[((base + 0) * 3 + 0) * 32 + il] = am0;
        Pp[((base + 0) * 3 + 1) * 32 + il] = a10;
        Pp[((base + 0) * 3 + 2) * 32 + il] = a20;
        Pp[((base + 1) * 3 + 0) * 32 + il] = am1;
        Pp[((base + 1) * 3 + 1) * 32 + il] = a11;
        Pp[((base + 1) * 3 + 2) * 32 + il] = a21;
        Pp[((base + 2) * 3 + 0) * 32 + il] = am2;
        Pp[((base + 2) * 3 + 1) * 32 + il] = a12;
        Pp[((base + 2) * 3 + 2) * 32 + il] = a22;
        Pp[((base + 3) * 3 + 0) * 32 + il] = am3;
        Pp[((base + 3) * 3 + 1) * 32 + il] = a13;
        Pp[((base + 3) * 3 + 2) * 32 + il] = a23;
    }
    __syncthreads();
    if (tid < 128) {
        const float* Pp = WTb;
        const int b = tid >> 5, ii = tid & 31;
        float sm = 0.f, s1 = 0.f, s2 = 0.f;
        #pragma unroll
        for (int t = 0; t < 8; ++t) {
            sm += Pp[((t * 4 + b) * 3 + 0) * 32 + ii];
            s1 += Pp[((t * 4 + b) * 3 + 1) * 32 + ii];
            s2 += Pp[((t * 4 + b) * 3 + 2) * 32 + ii];
        }
        w_out[(size_t)(b0 + b) * DIM + i0 + ii] = (sm + b_mem[i0 + ii]) * s1 + s2;
    }
}

// ---------------------------------------------------------------------------
// Kernel 2: per-b streaming pass over know (float4, 16 waves/block).
// ---------------------------------------------------------------------------
__global__ __launch_bounds__(1024) void read_kernel(
    const float* __restrict__ know,  // (BB, DIM, NN)
    const float* __restrict__ w,     // (BB, DIM)
    float* __restrict__ out)         // (BB, NN)
{
    __shared__ float  w_s[DIM];
    __shared__ float4 part_lg[16][50];
    __shared__ float4 part_ks[16][50];
    __shared__ float  tmp[256];
    __shared__ float  bc[2];

    const int tx  = threadIdx.x;       // 0..63 (lane)
    const int ty  = threadIdx.y;       // 0..15 (wave)
    const int tid = ty * 64 + tx;
    const int b   = blockIdx.x;

    if (tid < DIM) w_s[tid] = w[(size_t)b * DIM + tid];
    __syncthreads();

    float4 lg = make_float4(0.f, 0.f, 0.f, 0.f);
    float4 ks = make_float4(0.f, 0.f, 0.f, 0.f);
    if (tx < 49) {
        const float4* kp = (const float4*)(know + (size_t)b * DIM * NN) + (size_t)(ty * 32) * 49 + tx;
        const float*  wp = w_s + ty * 32;
        #pragma unroll 8
        for (int dd = 0; dd < 32; ++dd) {
            const float4 kv = kp[(size_t)dd * 49];
            const float  wv = wp[dd];
            lg.x = fmaf(kv.x, wv, lg.x); lg.y = fmaf(kv.y, wv, lg.y);
            lg.z = fmaf(kv.z, wv, lg.z); lg.w = fmaf(kv.w, wv, lg.w);
            ks.x += kv.x; ks.y += kv.y; ks.z += kv.z; ks.w += kv.w;
        }
        part_lg[ty][tx] = lg;
        part_ks[ty][tx] = ks;
    }
    __syncthreads();

    float lgn = 0.f, ksn = 0.f;
    if (tid < NN) {
        const int ng = tid >> 2, j = tid & 3;
        #pragma unroll
        for (int t = 0; t < 16; ++t) {
            lgn += ((const float*)&part_lg[t][ng])[j];
            ksn += ((const float*)&part_ks[t][ng])[j];
        }
    }

    if (tid < 256) tmp[tid] = (tid < NN) ? lgn : -FLT_MAX;
    __syncthreads();
    if (tid < 64) {
        float m = fmaxf(fmaxf(tmp[tid], tmp[tid + 64]),
                        fmaxf(tmp[tid + 128], tmp[tid + 192]));
        #pragma unroll
        for (int o = 32; o; o >>= 1) m = fmaxf(m, __shfl_down(m, o));
        if (tid == 0) bc[0] = m;
    }
    __syncthreads();

    const float e = (tid < NN) ? __expf(lgn - bc[0]) : 0.f;
    if (tid < 256) tmp[tid] = e;
    __syncthreads();
    if (tid < 64) {
        float s = tmp[tid] + tmp[tid + 64] + tmp[tid + 128] + tmp[tid + 192];
        #pragma unroll
        for (int o = 32; o; o >>= 1) s += __shfl_down(s, o);
        if (tid == 0) bc[1] = s;
    }
    __syncthreads();

    if (tid < NN) out[(size_t)b * NN + tid] = e / bc[1] * ksn;
}

// ---------------------------------------------------------------------------
extern "C" void kernel_launch(void* const* d_in, const int* in_sizes, int n_in,
                              void* d_out, int out_size, void* d_ws, size_t ws_size,
                              hipStream_t stream) {
    const float* memory   = (const float*)d_in[0];
    const float* know     = (const float*)d_in[1];
    const float* control  = (const float*)d_in[2];
    const float* W_mem    = (const float*)d_in[3];
    const float* b_mem    = (const float*)d_in[4];
    const float* W_concat = (const float*)d_in[5];
    // d_in[6] = b_concat : uniform over n -> softmax-invariant, unused
    const float* W_attn   = (const float*)d_in[7];
    // d_in[8] = b_attn   : same, unused
    float* outp = (float*)d_out;

    const size_t WCT_BYTES = (size_t)DIM * DIM * sizeof(float2);  // 2 MB
    const size_t W_BYTES   = (size_t)BB * DIM * sizeof(float);    // 512 KB

    if (ws_size >= WCT_BYTES + W_BYTES) {
        float2* wct  = (float2*)d_ws;
        float*  w_ws = (float*)((char*)d_ws + WCT_BYTES);
        transpose_kernel<<<dim3(8, 8), dim3(256), 0, stream>>>(W_concat, wct);
        prep_fast<<<dim3(BB / BT, DIM / IT), dim3(256), 0, stream>>>(
            memory, control, W_mem, b_mem, wct, W_attn, w_ws);
        read_kernel<<<dim3(BB), dim3(64, 16), 0, stream>>>(know, w_ws, outp);
    } else {
        float* w_ws = (float*)d_ws;
        prep_kernel<<<dim3(BB / BT, DIM / IT), dim3(256), 0, stream>>>(
            memory, control, W_mem, b_mem, W_concat, W_attn, w_ws);
        read_kernel<<<dim3(BB), dim3(64, 16), 0, stream>>>(know, w_ws, outp);
    }
}

// Round 6
// 37.088 us; speedup vs baseline: 1.0951x; 1.0951x over previous
//
#include <hip/hip_runtime.h>
#include <cfloat>

// Problem dims (fixed by reference)
#define BB   256   // batch
#define DIM  512
#define NN   196
#define BT   16    // b-tile in prep kernel
#define IT   32    // i-tile in prep kernel

// ---------------------------------------------------------------------------
// Kernel 1: prep — w[b,i] = (mem[b,i] + b_mem[i]) * v1[b,i] + v2[b,i]
//   mem[b,i] = sum_k memory[-1][b,k] * W_mem[k,i]
//   v1[b,i]  = sum_k u[b,k] * W_concat[i,     k]   (u = control[-1]*W_attn)
//   v2[b,i]  = sum_k u[b,k] * W_concat[DIM+i, k]
//
// grid (BB/BT, DIM/IT) = (16,16) = 256 blocks x 1024 thr (16 waves/CU).
// BT=16 -> weight traffic 49 MB total (4x less than r4's 196 MB).
// Thread (il = tid&31, bg = (tid>>5)&3, kg = tid>>7): 4 batches
// (b = bg*4..bg*4+3), k-slice [kg*8, kg*8+8) of each 64-k chunk.
// MU (m,u interleaved) staged once (64 KB, conflict-free [p][k] layout);
// W_concat chunk-transposed in LDS (r4-proven); kg-partials combined in LDS.
// ---------------------------------------------------------------------------
__global__ __launch_bounds__(1024, 1) void prep_kernel(
    const float* __restrict__ memory,    // (2,BB,DIM)
    const float* __restrict__ control,   // (2,BB,DIM)
    const float* __restrict__ W_mem,     // (DIM,DIM) row-major [k][i]
    const float* __restrict__ b_mem,     // (DIM)
    const float* __restrict__ W_concat,  // (2*DIM, DIM) row-major [c][j]
    const float* __restrict__ W_attn,    // (DIM,1)
    float* __restrict__ w_out)           // (BB, DIM)
{
    // MU[p][k] = (m[b0+2p][k], u[b0+2p][k], m[b0+2p+1][k], u[b0+2p+1][k])
    __shared__ float4 MU[8][DIM];    // 64 KB
    // buf: per-chunk WT float2[64][33] (16.9 KB), epilogue P[3][8kg][16b][32il] (48 KB)
    __shared__ float  buf[12288];    // 48 KB

    const int tid = threadIdx.x;
    const int il  = tid & 31;          // i within tile
    const int bg  = (tid >> 5) & 3;    // batch group (4 b's)
    const int kg  = tid >> 7;          // 0..7 k-slice owner
    const int b0  = blockIdx.x * BT;
    const int i0  = blockIdx.y * IT;

    const float* mem_in = memory  + (size_t)BB * DIM;  // memory[-1]
    const float* ctl_in = control + (size_t)BB * DIM;  // control[-1]

    // ---- stage MU once: 4096 float4 by 1024 threads, coalesced over k ----
    #pragma unroll
    for (int p4 = 0; p4 < 4; ++p4) {
        const int idx = p4 * 1024 + tid;   // 0..4095
        const int k   = idx & 511;
        const int pp  = idx >> 9;          // 0..7
        const int bb  = b0 + pp * 2;
        const float wa = W_attn[k];
        MU[pp][k] = make_float4(
            mem_in[(size_t)bb       * DIM + k],
            ctl_in[(size_t)bb       * DIM + k] * wa,
            mem_in[(size_t)(bb + 1) * DIM + k],
            ctl_in[(size_t)(bb + 1) * DIM + k] * wa);
    }

    float am[4] = {0.f, 0.f, 0.f, 0.f};
    float a1[4] = {0.f, 0.f, 0.f, 0.f};
    float a2[4] = {0.f, 0.f, 0.f, 0.f};

    // WT staging coords: thread loads one float4 of W1 or W2
    const int sr = tid >> 5;           // 0..31 i-row
    const int sc = tid & 15;           // 0..15 float4 col within 64-k chunk
    const int h  = (tid >> 4) & 1;     // 0 -> W1 row, 1 -> W2 row

    for (int kt = 0; kt < DIM; kt += 64) {
        __syncthreads();   // prev chunk compute done (covers MU on iter 0)

        // stage WT: (c1,c2) for k in [kt,kt+64), i in [i0,i0+32)
        {
            const float4 q = *(const float4*)&W_concat[
                (size_t)(h * DIM + i0 + sr) * DIM + kt + sc * 4];
            const int kb = sc * 4;
            buf[((kb + 0) * 33 + sr) * 2 + h] = q.x;
            buf[((kb + 1) * 33 + sr) * 2 + h] = q.y;
            buf[((kb + 2) * 33 + sr) * 2 + h] = q.z;
            buf[((kb + 3) * 33 + sr) * 2 + h] = q.w;
        }
        __syncthreads();

        // compute this thread's 8-k slice for its 4 batches
        #pragma unroll
        for (int kk = 0; kk < 8; ++kk) {
            const int kl = kg * 8 + kk;
            const int k  = kt + kl;
            const float  wm  = W_mem[(size_t)k * DIM + i0 + il];   // 128B/wave, L2
            const float2 c   = ((const float2*)buf)[kl * 33 + il]; // lane b64
            const float4 mu0 = MU[bg * 2 + 0][k];                  // bcast b128
            const float4 mu1 = MU[bg * 2 + 1][k];
            am[0] = fmaf(mu0.x, wm,  am[0]);
            a1[0] = fmaf(mu0.y, c.x, a1[0]);
            a2[0] = fmaf(mu0.y, c.y, a2[0]);
            am[1] = fmaf(mu0.z, wm,  am[1]);
            a1[1] = fmaf(mu0.w, c.x, a1[1]);
            a2[1] = fmaf(mu0.w, c.y, a2[1]);
            am[2] = fmaf(mu1.x, wm,  am[2]);
            a1[2] = fmaf(mu1.y, c.x, a1[2]);
            a2[2] = fmaf(mu1.y, c.y, a2[2]);
            am[3] = fmaf(mu1.z, wm,  am[3]);
            a1[3] = fmaf(mu1.w, c.x, a1[3]);
            a2[3] = fmaf(mu1.w, c.y, a2[3]);
        }
    }

    // ---- combine 8 kg-partials in LDS ----
    __syncthreads();
    #pragma unroll
    for (int j = 0; j < 4; ++j) {
        const int row = (kg * 16 + bg * 4 + j) * 32 + il;   // [kg][b][il]
        buf[row]        = am[j];
        buf[4096 + row] = a1[j];
        buf[8192 + row] = a2[j];
    }
    __syncthreads();
    if (tid < 512) {
        const int b = tid >> 5, ii = tid & 31;
        float sm = 0.f, s1 = 0.f, s2 = 0.f;
        #pragma unroll
        for (int t = 0; t < 8; ++t) {
            const int row = (t * 16 + b) * 32 + ii;
            sm += buf[row];
            s1 += buf[4096 + row];
            s2 += buf[8192 + row];
        }
        w_out[(size_t)(b0 + b) * DIM + i0 + ii] = (sm + b_mem[i0 + ii]) * s1 + s2;
    }
}

// ---------------------------------------------------------------------------
// Kernel 2: per-b streaming pass over know (float4, 16 waves/block).
// (byte-identical to rounds 2-5)
// ---------------------------------------------------------------------------
__global__ __launch_bounds__(1024) void read_kernel(
    const float* __restrict__ know,  // (BB, DIM, NN)
    const float* __restrict__ w,     // (BB, DIM)
    float* __restrict__ out)         // (BB, NN)
{
    __shared__ float  w_s[DIM];
    __shared__ float4 part_lg[16][50];
    __shared__ float4 part_ks[16][50];
    __shared__ float  tmp[256];
    __shared__ float  bc[2];

    const int tx  = threadIdx.x;       // 0..63 (lane)
    const int ty  = threadIdx.y;       // 0..15 (wave)
    const int tid = ty * 64 + tx;
    const int b   = blockIdx.x;

    if (tid < DIM) w_s[tid] = w[(size_t)b * DIM + tid];
    __syncthreads();

    float4 lg = make_float4(0.f, 0.f, 0.f, 0.f);
    float4 ks = make_float4(0.f, 0.f, 0.f, 0.f);
    if (tx < 49) {
        const float4* kp = (const float4*)(know + (size_t)b * DIM * NN) + (size_t)(ty * 32) * 49 + tx;
        const float*  wp = w_s + ty * 32;
        #pragma unroll 8
        for (int dd = 0; dd < 32; ++dd) {
            const float4 kv = kp[(size_t)dd * 49];
            const float  wv = wp[dd];
            lg.x = fmaf(kv.x, wv, lg.x); lg.y = fmaf(kv.y, wv, lg.y);
            lg.z = fmaf(kv.z, wv, lg.z); lg.w = fmaf(kv.w, wv, lg.w);
            ks.x += kv.x; ks.y += kv.y; ks.z += kv.z; ks.w += kv.w;
        }
        part_lg[ty][tx] = lg;
        part_ks[ty][tx] = ks;
    }
    __syncthreads();

    float lgn = 0.f, ksn = 0.f;
    if (tid < NN) {
        const int ng = tid >> 2, j = tid & 3;
        #pragma unroll
        for (int t = 0; t < 16; ++t) {
            lgn += ((const float*)&part_lg[t][ng])[j];
            ksn += ((const float*)&part_ks[t][ng])[j];
        }
    }

    if (tid < 256) tmp[tid] = (tid < NN) ? lgn : -FLT_MAX;
    __syncthreads();
    if (tid < 64) {
        float m = fmaxf(fmaxf(tmp[tid], tmp[tid + 64]),
                        fmaxf(tmp[tid + 128], tmp[tid + 192]));
        #pragma unroll
        for (int o = 32; o; o >>= 1) m = fmaxf(m, __shfl_down(m, o));
        if (tid == 0) bc[0] = m;
    }
    __syncthreads();

    const float e = (tid < NN) ? __expf(lgn - bc[0]) : 0.f;
    if (tid < 256) tmp[tid] = e;
    __syncthreads();
    if (tid < 64) {
        float s = tmp[tid] + tmp[tid + 64] + tmp[tid + 128] + tmp[tid + 192];
        #pragma unroll
        for (int o = 32; o; o >>= 1) s += __shfl_down(s, o);
        if (tid == 0) bc[1] = s;
    }
    __syncthreads();

    if (tid < NN) out[(size_t)b * NN + tid] = e / bc[1] * ksn;
}

// ---------------------------------------------------------------------------
extern "C" void kernel_launch(void* const* d_in, const int* in_sizes, int n_in,
                              void* d_out, int out_size, void* d_ws, size_t ws_size,
                              hipStream_t stream) {
    const float* memory   = (const float*)d_in[0];
    const float* know     = (const float*)d_in[1];
    const float* control  = (const float*)d_in[2];
    const float* W_mem    = (const float*)d_in[3];
    const float* b_mem    = (const float*)d_in[4];
    const float* W_concat = (const float*)d_in[5];
    // d_in[6] = b_concat : uniform over n -> softmax-invariant, unused
    const float* W_attn   = (const float*)d_in[7];
    // d_in[8] = b_attn   : same, unused
    float* w_ws = (float*)d_ws;          // (BB, DIM) = 512 KB scratch
    float* outp = (float*)d_out;         // (BB, NN) f32

    prep_kernel<<<dim3(BB / BT, DIM / IT), dim3(1024), 0, stream>>>(
        memory, control, W_mem, b_mem, W_concat, W_attn, w_ws);
    read_kernel<<<dim3(BB), dim3(64, 16), 0, stream>>>(know, w_ws, outp);
}